// Round 1
// baseline (1033.598 us; speedup 1.0000x reference)
//
#include <hip/hip_runtime.h>
#include <hip/hip_bf16.h>

#define B_ 4
#define T_ 4096
#define D_ 1024
#define R_ (B_*T_)
#define NB_ 16
#define RANK_ 64
#define NMEM_ 128
#define CHUNK_ 256
#define NCH_ (T_/CHUNK_)
#define EPS_ 1.1920929e-07f

__device__ __forceinline__ float silu_f(float v){ return v / (1.0f + expf(-v)); }

// ---------------- setup: a_seq, a_seq^CHUNK, depth gain ----------------
__global__ void setup_k(const float* __restrict__ logA_seq, const float* __restrict__ logdt_seq,
                        const float* __restrict__ logA_dep, const float* __restrict__ logdt_dep,
                        const int* __restrict__ active_k,
                        float* __restrict__ aseq, float* __restrict__ apowC, float* __restrict__ gain){
    int d = blockIdx.x*blockDim.x + threadIdx.x;
    if (d >= D_) return;
    float K = (float)(*active_k);
    float a = expf(-expf(logA_seq[d]) * expf(logdt_seq[d]));
    a = fmaxf(a, 1e-6f);              // matches jnp.maximum(a,1e-6) inside causal_scan
    aseq[d] = a;
    apowC[d] = powf(a, (float)CHUNK_);
    float g;
    if (d < NMEM_) {
        g = K;                        // a_depth == 1 exactly -> geom_gain -> K
    } else {
        float ad = expf(-expf(logA_dep[d-NMEM_]) * expf(logdt_dep[d-NMEM_]));
        float om = 1.0f - ad;
        if (fabsf(om) < 1e-6f) g = K;
        else g = (1.0f - powf(ad, K)) / fmaxf(om, 1e-8f);
    }
    gain[d] = g;
}

// ---------------- generic transpose: in[n][j][i] -> out[n][i][j] ----------------
__global__ void transpose_k(const float* __restrict__ in, float* __restrict__ out,
                            int nb, int rowsJ, int colsI){
    int idx = blockIdx.x*blockDim.x + threadIdx.x;
    int total = nb*rowsJ*colsI;
    if (idx >= total) return;
    int j = idx % rowsJ;
    int t = idx / rowsJ;
    int i = t % colsI;
    int n = t / colsI;
    out[idx] = in[(n*rowsJ + j)*colsI + i];
}

// ---------------- rms_norm(x) -> e ----------------
__global__ __launch_bounds__(256) void rms_k(const float* __restrict__ x, float* __restrict__ e){
    int row = blockIdx.x;
    int tid = threadIdx.x;
    const float4* xr = (const float4*)(x + (size_t)row*D_);
    float4 v = xr[tid];
    float ss = v.x*v.x + v.y*v.y + v.z*v.z + v.w*v.w;
    for (int off=32; off; off>>=1) ss += __shfl_down(ss, off, 64);
    __shared__ float red[4];
    if ((tid&63)==0) red[tid>>6] = ss;
    __syncthreads();
    float tot = red[0]+red[1]+red[2]+red[3];
    float scale = 1.0f / sqrtf(tot*(1.0f/D_) + EPS_);
    float4 o; o.x=v.x*scale; o.y=v.y*scale; o.z=v.z*scale; o.w=v.w*scale;
    ((float4*)(e + (size_t)row*D_))[tid] = o;
}

// ---------------- fused blockdiag seq+depth: drive=silu(e@Wseq), hdep=gain*silu(e@Wdep) ----------------
#define K2_ROWS 8
__global__ __launch_bounds__(256) void bd2_k(const float* __restrict__ e,
        const float* __restrict__ wseqT, const float* __restrict__ wdepT,
        const float* __restrict__ gain,
        float* __restrict__ drive, float* __restrict__ hdep){
    __shared__ float se[K2_ROWS][D_];
    int r0 = blockIdx.x * K2_ROWS;
    int tid = threadIdx.x;
    for (int rr=0; rr<K2_ROWS; ++rr)
        ((float4*)se[rr])[tid] = ((const float4*)(e + (size_t)(r0+rr)*D_))[tid];
    __syncthreads();
    for (int oo=0; oo<4; ++oo){
        int o = tid + 256*oo;
        int n = o >> 6, j = o & 63;
        const float* ws = wseqT + n*4096 + j;    // [n][i][j], step i*64 -> lane-coalesced
        const float* wd = wdepT + n*4096 + j;
        float accs[K2_ROWS], accd[K2_ROWS];
        #pragma unroll
        for (int rr=0;rr<K2_ROWS;++rr){ accs[rr]=0.f; accd[rr]=0.f; }
        #pragma unroll 4
        for (int i=0;i<64;++i){
            float wsv = ws[i*64], wdv = wd[i*64];
            #pragma unroll
            for (int rr=0; rr<K2_ROWS; ++rr){
                float ev = se[rr][n*64+i];       // wave-uniform broadcast
                accs[rr] += wsv*ev; accd[rr] += wdv*ev;
            }
        }
        float g = gain[o];
        #pragma unroll
        for (int rr=0; rr<K2_ROWS; ++rr){
            drive[(size_t)(r0+rr)*D_ + o] = silu_f(accs[rr]);
            hdep [(size_t)(r0+rr)*D_ + o] = g*silu_f(accd[rr]);
        }
    }
}

// ---------------- scan pass 1: local chunk scan in place, emit chunk finals ----------------
__global__ __launch_bounds__(256) void scan1_k(float* __restrict__ h, const float* __restrict__ aseq,
                                               float* __restrict__ carry){
    int tid = blockIdx.x*256 + threadIdx.x;   // B_*NCH_*D_ = 65536 threads
    int d  = tid & (D_-1);
    int bc = tid >> 10;                        // b*NCH_ + c
    int c  = bc & (NCH_-1);
    int b  = bc >> 4;
    float a = aseq[d];
    size_t base = ((size_t)(b*T_ + c*CHUNK_))*D_ + d;
    float hh = 0.f;
    for (int s=0; s<CHUNK_; ++s){
        float v = h[base + (size_t)s*D_];
        hh = a*hh + v;
        h[base + (size_t)s*D_] = hh;
    }
    carry[(size_t)bc*D_ + d] = hh;
}

// ---------------- scan pass 2: serial prefix over the 16 chunk finals ----------------
__global__ __launch_bounds__(256) void scan2_k(float* __restrict__ carry, const float* __restrict__ apowC){
    int tid = blockIdx.x*256 + threadIdx.x;   // B_*D_ = 4096 threads
    int d = tid & (D_-1);
    int b = tid >> 10;
    float aC = apowC[d];
    float pref = 0.f;
    for (int c=0;c<NCH_;++c){
        size_t idx = (size_t)(b*NCH_+c)*D_ + d;
        float s = carry[idx];
        carry[idx] = pref;                     // carry-in for chunk c
        pref = aC*pref + s;
    }
}

// ---------------- scan pass 3: apply carry, add h_depth -> final h ----------------
__global__ __launch_bounds__(256) void scan3_k(float* __restrict__ h, const float* __restrict__ hdep,
                                               const float* __restrict__ aseq, const float* __restrict__ carry){
    int tid = blockIdx.x*256 + threadIdx.x;
    int d  = tid & (D_-1);
    int bc = tid >> 10;
    int c  = bc & (NCH_-1);
    int b  = bc >> 4;
    float a = aseq[d];
    float P = carry[(size_t)bc*D_ + d];
    size_t base = ((size_t)(b*T_ + c*CHUNK_))*D_ + d;
    float apow = a;
    for (int s=0;s<CHUNK_;++s){
        size_t idx = base + (size_t)s*D_;
        h[idx] = h[idx] + P*apow + hdep[idx];
        apow *= a;
    }
}

// ---------------- r = silu(blockdiag(concat[rms(h), e, shifted_e], w_post)) ----------------
#define K6_ROWS 4
__global__ __launch_bounds__(256) void post_k(const float* __restrict__ h, const float* __restrict__ e,
        const float* __restrict__ wpostT, float* __restrict__ rout){
    __shared__ float sc[K6_ROWS][3*D_];
    __shared__ float redl[4];
    int r0 = blockIdx.x*K6_ROWS;
    int tid = threadIdx.x;
    for (int rr=0; rr<K6_ROWS; ++rr){
        size_t row = (size_t)(r0+rr);
        float4 hv = ((const float4*)(h + row*D_))[tid];
        float ss = hv.x*hv.x+hv.y*hv.y+hv.z*hv.z+hv.w*hv.w;
        for (int off=32; off; off>>=1) ss += __shfl_down(ss, off, 64);
        if ((tid&63)==0) redl[tid>>6] = ss;
        __syncthreads();
        float tot = redl[0]+redl[1]+redl[2]+redl[3];
        float scale = 1.0f / sqrtf(tot*(1.0f/D_) + EPS_);
        float4 o; o.x=hv.x*scale; o.y=hv.y*scale; o.z=hv.z*scale; o.w=hv.w*scale;
        ((float4*)&sc[rr][0])[tid] = o;
        ((float4*)&sc[rr][D_])[tid] = ((const float4*)(e + row*D_))[tid];
        int t = (int)(row & (T_-1));
        float4 sv;
        if (t == 0) { sv = make_float4(0.f,0.f,0.f,0.f); }
        else        { sv = ((const float4*)(e + (row-1)*D_))[tid]; }
        ((float4*)&sc[rr][2*D_])[tid] = sv;
        __syncthreads();   // also protects redl reuse next iteration
    }
    for (int oo=0; oo<4; ++oo){
        int o = tid + 256*oo;
        int n = o>>6, j = o&63;
        const float* w = wpostT + n*(192*64) + j;
        float acc[K6_ROWS] = {0.f,0.f,0.f,0.f};
        #pragma unroll 2
        for (int i=0;i<192;++i){
            float wv = w[i*64];
            #pragma unroll
            for (int rr=0;rr<K6_ROWS;++rr) acc[rr] += wv * sc[rr][n*192+i];
        }
        #pragma unroll
        for (int rr=0;rr<K6_ROWS;++rr)
            rout[(size_t)(r0+rr)*D_ + o] = silu_f(acc[rr]);
    }
}

// ---------------- out = x + blockdiag(r,w_local) + (r@lrB^T)@lrA^T ----------------
#define K7_ROWS 4
__global__ __launch_bounds__(256) void out_k(const float* __restrict__ x, const float* __restrict__ r,
        const float* __restrict__ wlocT, const float* __restrict__ lrBT, const float* __restrict__ lrAT,
        float* __restrict__ out){
    __shared__ float sr[K7_ROWS][D_];
    __shared__ float plow[4][K7_ROWS][RANK_];
    __shared__ float rlow[K7_ROWS][RANK_];
    int r0 = blockIdx.x*K7_ROWS;
    int tid = threadIdx.x;
    for (int rr=0;rr<K7_ROWS;++rr)
        ((float4*)sr[rr])[tid] = ((const float4*)(r + (size_t)(r0+rr)*D_))[tid];
    __syncthreads();
    {   // rlow partials: lane k over rank, wave p over quarters of D
        int k = tid & 63, p = tid >> 6;
        float acc[K7_ROWS] = {0.f,0.f,0.f,0.f};
        for (int i=p*256; i<p*256+256; ++i){
            float w = lrBT[i*64 + k];            // lane-coalesced
            #pragma unroll
            for (int rr=0;rr<K7_ROWS;++rr) acc[rr] += w * sr[rr][i];
        }
        #pragma unroll
        for (int rr=0;rr<K7_ROWS;++rr) plow[p][rr][k] = acc[rr];
    }
    __syncthreads();
    {   int rr = tid>>6, kk = tid&63;
        rlow[rr][kk] = plow[0][rr][kk]+plow[1][rr][kk]+plow[2][rr][kk]+plow[3][rr][kk];
    }
    __syncthreads();
    for (int oo=0;oo<4;++oo){
        int o = tid + 256*oo;
        int n = o>>6, j = o&63;
        const float* wl = wlocT + n*4096 + j;
        float acc[K7_ROWS]={0.f,0.f,0.f,0.f};
        #pragma unroll 4
        for (int i=0;i<64;++i){
            float wv = wl[i*64];
            #pragma unroll
            for (int rr=0;rr<K7_ROWS;++rr) acc[rr] += wv * sr[rr][n*64+i];
        }
        #pragma unroll 4
        for (int kk=0;kk<64;++kk){
            float av = lrAT[kk*1024 + o];        // lane-coalesced
            #pragma unroll
            for (int rr=0;rr<K7_ROWS;++rr) acc[rr] += av * rlow[rr][kk];
        }
        #pragma unroll
        for (int rr=0;rr<K7_ROWS;++rr){
            size_t idx = (size_t)(r0+rr)*D_ + o;
            out[idx] = x[idx] + acc[rr];
        }
    }
}

extern "C" void kernel_launch(void* const* d_in, const int* in_sizes, int n_in,
                              void* d_out, int out_size, void* d_ws, size_t ws_size,
                              hipStream_t stream) {
    const float* x         = (const float*)d_in[0];
    const int*   active_k  = (const int*)  d_in[1];
    const float* b_seq_w   = (const float*)d_in[2];
    const float* b_depth_w = (const float*)d_in[3];
    const float* w_post_w  = (const float*)d_in[4];
    const float* w_local_w = (const float*)d_in[5];
    const float* lr_A      = (const float*)d_in[6];
    const float* lr_B      = (const float*)d_in[7];
    const float* logA_seq  = (const float*)d_in[8];
    const float* logdt_seq = (const float*)d_in[9];
    const float* logA_dep  = (const float*)d_in[10];
    const float* logdt_dep = (const float*)d_in[11];

    float* ws = (float*)d_ws;
    float* e      = ws;
    float* h      = e + (size_t)R_*D_;
    float* rbuf   = h + (size_t)R_*D_;          // h_depth, then r
    float* carry  = rbuf + (size_t)R_*D_;       // B_*NCH_*D_
    float* aseq   = carry + (size_t)B_*NCH_*D_;
    float* apowC  = aseq + D_;
    float* gain   = apowC + D_;
    float* wseqT  = gain + D_;                  // 16*64*64
    float* wdepT  = wseqT + 65536;
    float* wpostT = wdepT + 65536;              // 16*192*64
    float* wlocT  = wpostT + 196608;
    float* lrBT   = wlocT + 65536;              // [1024][64]
    float* lrAT   = lrBT + 65536;               // [64][1024]

    setup_k<<<4, 256, 0, stream>>>(logA_seq, logdt_seq, logA_dep, logdt_dep, active_k,
                                   aseq, apowC, gain);
    transpose_k<<<(65536+255)/256, 256, 0, stream>>>(b_seq_w,   wseqT, 16, 64, 64);
    transpose_k<<<(65536+255)/256, 256, 0, stream>>>(b_depth_w, wdepT, 16, 64, 64);
    transpose_k<<<(196608+255)/256,256, 0, stream>>>(w_post_w,  wpostT,16, 64, 192);
    transpose_k<<<(65536+255)/256, 256, 0, stream>>>(w_local_w, wlocT, 16, 64, 64);
    transpose_k<<<(65536+255)/256, 256, 0, stream>>>(lr_B,      lrBT,   1, 64, 1024);
    transpose_k<<<(65536+255)/256, 256, 0, stream>>>(lr_A,      lrAT,   1, 1024, 64);

    rms_k  <<<R_, 256, 0, stream>>>(x, e);
    bd2_k  <<<R_/K2_ROWS, 256, 0, stream>>>(e, wseqT, wdepT, gain, h, rbuf);
    scan1_k<<<(B_*NCH_*D_)/256, 256, 0, stream>>>(h, aseq, carry);
    scan2_k<<<(B_*D_)/256, 256, 0, stream>>>(carry, apowC);
    scan3_k<<<(B_*NCH_*D_)/256, 256, 0, stream>>>(h, rbuf, aseq, carry);
    post_k <<<R_/K6_ROWS, 256, 0, stream>>>(h, e, wpostT, rbuf);
    out_k  <<<R_/K7_ROWS, 256, 0, stream>>>(x, rbuf, wlocT, lrBT, lrAT, (float*)d_out);
}